// Round 1
// 512.927 us; speedup vs baseline: 1.0016x; 1.0016x over previous
//
#include <hip/hip_runtime.h>
#include <math.h>

// Fused: per-position dual C=64 -> 1 projections + LeakyReLU(0.3) + sigmoid gate.
// Memory-bound: 512 MiB read / 4 MiB write -> ~86 us floor at 6.3 TB/s.
//
// Layout (v2): 4 lanes per position, quad-interleaved float4 ownership.
//   lane q of a quad owns float4 indices {q, q+4, q+8, q+12} of the
//   position's 16 float4s (16 channels per lane).
//   - 8 independent 16B global loads per thread, issued back-to-back:
//     8 KiB in flight per wave (4x the previous layout's 2 KiB) -> hides
//     HBM latency without relying on deep occupancy.
//   - each load instruction touches sixteen 64B lines, each FULLY consumed
//     (4 contiguous lanes cover 64B of one position, 16 positions/wave).
//   - reduction is only 2 butterfly rounds over 4 lanes (4 ds ops per
//     position vs 8 before), chain depth halved.
// One-shot grid: 4*npos threads, no grid-stride loop; wave churn keeps a
// continuous stream of fresh loads in the memory system.

#define NEG_SLOPE 0.3f

__device__ __forceinline__ float dot4(const float4 a, const float4 w, float acc) {
    acc = fmaf(a.x, w.x, acc);
    acc = fmaf(a.y, w.y, acc);
    acc = fmaf(a.z, w.z, acc);
    acc = fmaf(a.w, w.w, acc);
    return acc;
}

__global__ __launch_bounds__(256) void attn_gate_kernel(
    const float* __restrict__ xatt,
    const float* __restrict__ xsaut,
    const float* __restrict__ W_act,   // [64]
    const float* __restrict__ b_act,   // [1]
    const float* __restrict__ W_saut,  // [64]
    const float* __restrict__ b_saut,  // [1]
    const float* __restrict__ W2,      // [1]
    const float* __restrict__ b2,      // [1]
    float* __restrict__ out,
    int npos)                          // B*L
{
    const int tid = blockIdx.x * blockDim.x + threadIdx.x;
    const int pos = tid >> 2;          // 4 lanes per position
    const int q   = tid & 3;           // quad lane: owns float4s {q, q+4, q+8, q+12}
    if (pos >= npos) return;

    // Uniform scalars (compiler emits s_load; L1/K$-resident).
    const float ba = b_act[0];
    const float bs = b_saut[0];
    const float w2 = W2[0];
    const float c2 = b2[0];

    const float4* __restrict__ a4 = (const float4*)xatt;
    const float4* __restrict__ s4 = (const float4*)xsaut;
    const long base = (long)pos * 16 + q;   // float4 index

    // 8 independent HBM loads issued first (the long poles).
    const float4 a0 = a4[base +  0];
    const float4 a1 = a4[base +  4];
    const float4 a2 = a4[base +  8];
    const float4 a3 = a4[base + 12];
    const float4 s0 = s4[base +  0];
    const float4 s1 = s4[base +  4];
    const float4 s2 = s4[base +  8];
    const float4 s3 = s4[base + 12];

    // Weight fragments: tiny, L1-hot after the first waves.
    const float4* __restrict__ wA = (const float4*)W_act;
    const float4* __restrict__ wS = (const float4*)W_saut;
    const float4 wa0 = wA[q +  0];
    const float4 wa1 = wA[q +  4];
    const float4 wa2 = wA[q +  8];
    const float4 wa3 = wA[q + 12];
    const float4 ws0 = wS[q +  0];
    const float4 ws1 = wS[q +  4];
    const float4 ws2 = wS[q +  8];
    const float4 ws3 = wS[q + 12];

    float pa = dot4(a3, wa3, dot4(a2, wa2, dot4(a1, wa1, dot4(a0, wa0, 0.0f))));
    float ps = dot4(s3, ws3, dot4(s2, ws2, dot4(s1, ws1, dot4(s0, ws0, 0.0f))));

    // Butterfly reduce across the 4 lanes of the quad (2 rounds, 2 values).
    pa += __shfl_xor(pa, 1, 4);
    pa += __shfl_xor(pa, 2, 4);
    ps += __shfl_xor(ps, 1, 4);
    ps += __shfl_xor(ps, 2, 4);

    if (q == 0) {
        const float xs = ps + bs;
        float h = (pa + ba) + xs;
        h = (h >= 0.0f) ? h : NEG_SLOPE * h;
        const float z = fmaf(h, w2, c2);
        const float g = 1.0f / (1.0f + __expf(-z));
        out[pos] = g * xs;
    }
}

extern "C" void kernel_launch(void* const* d_in, const int* in_sizes, int n_in,
                              void* d_out, int out_size, void* d_ws, size_t ws_size,
                              hipStream_t stream) {
    const float* xatt   = (const float*)d_in[0];
    const float* xsaut  = (const float*)d_in[1];
    const float* W_act  = (const float*)d_in[2];
    const float* b_act  = (const float*)d_in[3];
    const float* W_saut = (const float*)d_in[4];
    const float* b_saut = (const float*)d_in[5];
    const float* W2     = (const float*)d_in[6];
    const float* b2     = (const float*)d_in[7];
    float* out = (float*)d_out;

    const int npos = out_size;  // B*L positions, one output each

    // One thread-quad per position: 4*npos threads, one-shot (no loop).
    const int threads = 256;
    const int blocks  = (int)(((long)npos * 4 + threads - 1) / threads);  // 16384
    attn_gate_kernel<<<blocks, threads, 0, stream>>>(
        xatt, xsaut, W_act, b_act, W_saut, b_saut, W2, b2, out, npos);
}

// Round 3
// 487.689 us; speedup vs baseline: 1.0535x; 1.0517x over previous
//
#include <hip/hip_runtime.h>
#include <math.h>

// Fused: per-position dual C=64 -> 1 projections + LeakyReLU(0.3) + sigmoid gate.
// Memory-bound: 512 MiB read / 4 MiB write -> ~85 us floor at 6.3 TB/s.
//
// v4 = v3 (non-temporal streaming) with the compile fix: the nontemporal
// builtins require native clang vector types, not HIP_vector_type. Use
// ext_vector_type(4) float for the 16B streaming loads.
//
// Evidence trail: v1 (16 lanes/pos, contiguous, grid-stride) and v2
// (4 lanes/pos, quad-scattered, one-shot, 4x MLP) BOTH pin at ~160 us
// (3.36 TB/s delivered) with VALUBusy <12%, occupancy ~75%, HBM 21%.
// FETCH_SIZE == exactly half the input => the 256 MiB Infinity Cache
// serves its capacity worth and the whole 537 MB stream passes THROUGH
// the MALL fill/evict path every iteration. Theory: MALL read-ingest
// saturates ~3.4 TB/s and is the shared choke both kernel shapes hit.
// Fix: nt loads skip cache allocation -> stream doesn't churn the MALL.
// Weights stay cached (reused by every wave).
//
// Fingerprint if correct: FETCH_SIZE *rises* to ~537 MB while dur_us
// *drops* to ~90-105 us.

#define NEG_SLOPE 0.3f

typedef float vf4 __attribute__((ext_vector_type(4)));

__device__ __forceinline__ float dot4v(const vf4 a, const float4 w, float acc) {
    acc = fmaf(a.x, w.x, acc);
    acc = fmaf(a.y, w.y, acc);
    acc = fmaf(a.z, w.z, acc);
    acc = fmaf(a.w, w.w, acc);
    return acc;
}

__global__ __launch_bounds__(256) void attn_gate_kernel(
    const float* __restrict__ xatt,
    const float* __restrict__ xsaut,
    const float* __restrict__ W_act,   // [64]
    const float* __restrict__ b_act,   // [1]
    const float* __restrict__ W_saut,  // [64]
    const float* __restrict__ b_saut,  // [1]
    const float* __restrict__ W2,      // [1]
    const float* __restrict__ b2,      // [1]
    float* __restrict__ out,
    int npos)                          // B*L
{
    const int tid = blockIdx.x * blockDim.x + threadIdx.x;
    const int pos = tid >> 2;          // 4 lanes per position
    const int q   = tid & 3;           // quad lane: owns float4s {q, q+4, q+8, q+12}
    if (pos >= npos) return;

    // Uniform scalars (s_load; K$-resident).
    const float ba = b_act[0];
    const float bs = b_saut[0];
    const float w2 = W2[0];
    const float c2 = b2[0];

    const vf4* __restrict__ a4 = (const vf4*)xatt;
    const vf4* __restrict__ s4 = (const vf4*)xsaut;
    const long base = (long)pos * 16 + q;   // float4 index

    // 8 independent streaming loads, NON-TEMPORAL (global_load_dwordx4 nt):
    // no cache allocation for the 537 MB once-through stream.
    const vf4 a0 = __builtin_nontemporal_load(a4 + base +  0);
    const vf4 a1 = __builtin_nontemporal_load(a4 + base +  4);
    const vf4 a2 = __builtin_nontemporal_load(a4 + base +  8);
    const vf4 a3 = __builtin_nontemporal_load(a4 + base + 12);
    const vf4 s0 = __builtin_nontemporal_load(s4 + base +  0);
    const vf4 s1 = __builtin_nontemporal_load(s4 + base +  4);
    const vf4 s2 = __builtin_nontemporal_load(s4 + base +  8);
    const vf4 s3 = __builtin_nontemporal_load(s4 + base + 12);

    // Weight fragments: tiny and reused by every wave -> keep CACHED.
    const float4* __restrict__ wA = (const float4*)W_act;
    const float4* __restrict__ wS = (const float4*)W_saut;
    const float4 wa0 = wA[q +  0];
    const float4 wa1 = wA[q +  4];
    const float4 wa2 = wA[q +  8];
    const float4 wa3 = wA[q + 12];
    const float4 ws0 = wS[q +  0];
    const float4 ws1 = wS[q +  4];
    const float4 ws2 = wS[q +  8];
    const float4 ws3 = wS[q + 12];

    float pa = dot4v(a3, wa3, dot4v(a2, wa2, dot4v(a1, wa1, dot4v(a0, wa0, 0.0f))));
    float ps = dot4v(s3, ws3, dot4v(s2, ws2, dot4v(s1, ws1, dot4v(s0, ws0, 0.0f))));

    // Butterfly reduce across the 4 lanes of the quad (2 rounds, 2 values).
    pa += __shfl_xor(pa, 1, 4);
    pa += __shfl_xor(pa, 2, 4);
    ps += __shfl_xor(ps, 1, 4);
    ps += __shfl_xor(ps, 2, 4);

    if (q == 0) {
        const float xs = ps + bs;
        float h = (pa + ba) + xs;
        h = (h >= 0.0f) ? h : NEG_SLOPE * h;
        const float z = fmaf(h, w2, c2);
        const float g = 1.0f / (1.0f + __expf(-z));
        __builtin_nontemporal_store(g * xs, out + pos);
    }
}

extern "C" void kernel_launch(void* const* d_in, const int* in_sizes, int n_in,
                              void* d_out, int out_size, void* d_ws, size_t ws_size,
                              hipStream_t stream) {
    const float* xatt   = (const float*)d_in[0];
    const float* xsaut  = (const float*)d_in[1];
    const float* W_act  = (const float*)d_in[2];
    const float* b_act  = (const float*)d_in[3];
    const float* W_saut = (const float*)d_in[4];
    const float* b_saut = (const float*)d_in[5];
    const float* W2     = (const float*)d_in[6];
    const float* b2     = (const float*)d_in[7];
    float* out = (float*)d_out;

    const int npos = out_size;  // B*L positions, one output each

    // One thread-quad per position: 4*npos threads, one-shot (no loop).
    const int threads = 256;
    const int blocks  = (int)(((long)npos * 4 + threads - 1) / threads);  // 16384
    attn_gate_kernel<<<blocks, threads, 0, stream>>>(
        xatt, xsaut, W_act, b_act, W_saut, b_saut, W2, b2, out, npos);
}